// Round 10
// baseline (131.687 us; speedup 1.0000x reference)
//
#include <hip/hip_runtime.h>
#include <stdint.h>

// BlockAttention: B=8, S=8192, D=H=128, BLOCK=256, WINDOW=256 (halo 255, W=766)
// No softmax => out_blk = x_blk @ N_n + 1 (x) bqM_n   (Q never materialized)
//   M_n^T = sum_{j=2n-2}^{2n+3} Chalf_j^T - v_a(x)k_a - v_z(x)k_z
//   Chalf_j^T[h][d] = sum over half j's 128 keys of v[h]*k[d]  (f32)
//   N_n = Wq^T (scale*M_n),  bqM_n[h] = sum_f bq[f]*(scale*M_n)[f][h]
//   a=(n-1)*256 = col 0 of even half 2n-2 (slot0), z=(n+1)*256+255 = col 127
//   of odd half 2n+3 (slot1).
// kv_kernel:  512 blocks (b, half j) x 256 thr, 69.6 KB LDS => 2 blocks/CU
//   (co-resident blocks hide each other's barriers). 4 phases:
//   stage Wk+Wv | K+V GEMM | both transposes | Chalf-GEMM -> Cpart + edges.
// attn_kernel: 256 blocks (b,n) x 512 thr, 2 barriers: phase A (6 half-C sums,
//   rank-1 edges, bqM reduce) -> m_l; N-GEMM -> n_l; O = x*N + bias.
// Both grids: bijective XCD swizzle => XCD k owns batch k (C L2-local).

#define B_ 8
#define S_ 8192
#define LDW 136   // padded leading dim (shorts): 272B rows, 16B-aligned

using bf16x8 = __attribute__((ext_vector_type(8))) short;   // 8 bf16 = 4 VGPRs
using s16x4  = __attribute__((ext_vector_type(4))) short;
using f32x16 = __attribute__((ext_vector_type(16))) float;

__device__ __forceinline__ short f2bf(float f) {
  union { float f; uint32_t u; } v; v.f = f;
  uint32_t r = v.u + 0x7fffu + ((v.u >> 16) & 1u);   // RNE
  return (short)(r >> 16);
}
__device__ __forceinline__ float bf2f(short s) {
  union { uint32_t u; float f; } v; v.u = ((uint32_t)(uint16_t)s) << 16;
  return v.f;
}

// ---------------------------------------------------------------------------
// kv_kernel: 512 blocks (b, half j) x 256 threads (4 waves), 128 keys each.
// LDS: areaA + areaB, each [128][LDW] bf16 = 34,816 B; total 69,632 B
//  => 2 blocks/CU (160 KB LDS/CU), 8 waves/CU.
// ---------------------------------------------------------------------------
__global__ __launch_bounds__(256) void kv_kernel(
    const float* __restrict__ x,
    const float* __restrict__ Wk, const float* __restrict__ bk,
    const float* __restrict__ Wv, const float* __restrict__ bv,
    float* __restrict__ Cpart, short* __restrict__ kedge,
    short* __restrict__ vedge)
{
  __shared__ __align__(16) short areaA[128 * LDW];   // Wk stage -> K^T tile [d][s]
  __shared__ __align__(16) short areaB[128 * LDW];   // Wv stage -> V^T tile [h][s]

  const int tid  = threadIdx.x;
  const int lane = tid & 63;
  const int wv   = tid >> 6;        // 0..3
  const int c    = lane & 31;
  const int hl   = lane >> 5;
  // bijective XCD swizzle (512 % 8 == 0): XCD k owns wg k*64..+64 (= batch k)
  const int wg   = ((int)blockIdx.x & 7) * 64 + ((int)blockIdx.x >> 3);
  const int r0   = wg * 128;
  const int b    = r0 >> 13;
  const int j    = (r0 & (S_ - 1)) >> 7;   // half index 0..63

  // A fragments from x: A[m=c][k=16*kst+8*hl+jj], rows r0 + wv*32 + c
  bf16x8 afrag[8];
  {
    const float* xrow = x + (size_t)(r0 + wv * 32 + c) * 128 + hl * 8;
    #pragma unroll
    for (int kst = 0; kst < 8; ++kst) {
      const float4* p = (const float4*)(xrow + kst * 16);
      float4 f0 = p[0], f1 = p[1];
      bf16x8 a;
      a[0] = f2bf(f0.x); a[1] = f2bf(f0.y); a[2] = f2bf(f0.z); a[3] = f2bf(f0.w);
      a[4] = f2bf(f1.x); a[5] = f2bf(f1.y); a[6] = f2bf(f1.z); a[7] = f2bf(f1.w);
      afrag[kst] = a;
    }
  }

  auto stageW = [&](const float* W, short* wl) {   // 128x128 f32 -> bf16
    #pragma unroll
    for (int it = 0; it < 16; ++it) {
      int l  = it * 256 + tid;
      int nn = l >> 5;
      int k4 = (l & 31) << 2;
      const float4 f = *(const float4*)(W + nn * 128 + k4);
      s16x4 o;
      o[0] = f2bf(f.x); o[1] = f2bf(f.y); o[2] = f2bf(f.z); o[3] = f2bf(f.w);
      *(s16x4*)(wl + nn * LDW + k4) = o;
    }
  };

  auto gemm = [&](const float* bias, f32x16* acc, const short* wl) {
    #pragma unroll
    for (int nt = 0; nt < 4; ++nt) {
      float bvv = bias[nt * 32 + c];
      #pragma unroll
      for (int i = 0; i < 16; ++i) acc[nt][i] = bvv;
    }
    #pragma unroll
    for (int kst = 0; kst < 8; ++kst) {
      #pragma unroll
      for (int nt = 0; nt < 4; ++nt) {
        bf16x8 bb = *(const bf16x8*)(wl + (nt * 32 + c) * LDW + kst * 16 + hl * 8);
        acc[nt] = __builtin_amdgcn_mfma_f32_32x32x16_bf16(afrag[kst], bb, acc[nt], 0, 0, 0);
      }
    }
  };

  // C-tile layout: col=lane&31, row=(reg&3)+8*(reg>>2)+4*hl
  auto writeTransposedLDS = [&](f32x16* acc, short* wl) {   // wl[d][s], s 0..127
    #pragma unroll
    for (int nt = 0; nt < 4; ++nt) {
      int d = nt * 32 + c;
      #pragma unroll
      for (int g = 0; g < 4; ++g) {
        #pragma unroll
        for (int p = 0; p < 2; ++p) {
          int reg = g * 4 + p * 2;
          int sl  = wv * 32 + g * 8 + hl * 4 + p * 2;   // 0..127
          uint32_t pk = (uint32_t)(uint16_t)f2bf(acc[nt][reg]) |
                        ((uint32_t)(uint16_t)f2bf(acc[nt][reg + 1]) << 16);
          *(uint32_t*)(wl + d * LDW + sl) = pk;
        }
      }
    }
  };

  // ---- P1: stage Wk -> A, Wv -> B ----
  stageW(Wk, areaA);
  stageW(Wv, areaB);
  __syncthreads();

  // ---- P2: K GEMM(A) + V GEMM(B) ----
  f32x16 kacc[4], vacc[4];
  gemm(bk, kacc, areaA);
  gemm(bv, vacc, areaB);
  __syncthreads();                   // weight reads done

  // ---- P3: K^T -> A, V^T -> B ----
  writeTransposedLDS(kacc, areaA);
  writeTransposedLDS(vacc, areaB);
  __syncthreads();

  // ---- P4: Chalf-GEMM + edges + Cpart ----
  {
    f32x16 cacc[4];
    #pragma unroll
    for (int nt = 0; nt < 4; ++nt)
      #pragma unroll
      for (int i = 0; i < 16; ++i) cacc[nt][i] = 0.f;

    #pragma unroll
    for (int kst = 0; kst < 8; ++kst) {
      bf16x8 a = *(const bf16x8*)(areaB + (wv * 32 + c) * LDW + kst * 16 + hl * 8);
      #pragma unroll
      for (int nt = 0; nt < 4; ++nt) {
        bf16x8 bb = *(const bf16x8*)(areaA + (nt * 32 + c) * LDW + kst * 16 + hl * 8);
        cacc[nt] = __builtin_amdgcn_mfma_f32_32x32x16_bf16(a, bb, cacc[nt], 0, 0, 0);
      }
    }

    // edge rows: even half -> col 0 = key j*128 (slot 0 of block j/2);
    //            odd half  -> col 127 = key j*128+127 (slot 1).
    {
      const int slot = j & 1;
      const int col  = slot ? 127 : 0;
      size_t eo = ((size_t)(b * 32 + (j >> 1))) * 256 + slot * 128;
      if (tid < 128)      kedge[eo + tid]         = areaA[tid * LDW + col];
      else                vedge[eo + (tid - 128)] = areaB[(tid - 128) * LDW + col];
    }

    float* Cp = Cpart + ((size_t)(b * 64 + j)) * 16384;   // [h][d] row-major
    #pragma unroll
    for (int nt = 0; nt < 4; ++nt) {
      #pragma unroll
      for (int reg = 0; reg < 16; ++reg) {
        int row = (reg & 3) + 8 * (reg >> 2) + 4 * hl;
        Cp[(wv * 32 + row) * 128 + nt * 32 + c] = cacc[nt][reg];
      }
    }
  }
}

// ---------------------------------------------------------------------------
// attn_kernel: 256 blocks (b,n) x 512 threads (8 waves). Q-free.
// Phase A: m[h][f] = scale*(sum 6 half-C - v_a k_a - v_z k_z); bqM reduce;
//          m_l bf16.  (thread owns h = i4*16+(tid>>5), f = (tid&31)*4..+3)
// N-GEMM:  N2[h][d] = sum_f m_l[h][f] * wqT[d][f]
// O-GEMM:  O[s][h]  = sum_d x[s][d] * n_l[h][d] + bqM[h]
// LDS: wqT 34,816 | m_l 34,816 | n_l 34,816 | bqM 512; opat aliases [0,36864).
// ---------------------------------------------------------------------------
__global__ __launch_bounds__(512) void attn_kernel(
    const float* __restrict__ x,
    const float* __restrict__ Wq, const float* __restrict__ bq,
    const float* __restrict__ Cpart,
    const short* __restrict__ kedge, const short* __restrict__ vedge,
    float* __restrict__ out)
{
  __shared__ __align__(16) char smem[104960];
  short* wqT   = (short*)smem;             // [d][f] transposed Wq, bf16
  short* m_l   = (short*)(smem + 34816);   // [h][f] scale*M^T, bf16
  short* n_l   = (short*)(smem + 69632);   // [h][d] N2, bf16
  float* bqM_l = (float*)(smem + 104448);  // [128]
  float* opat  = (float*)smem;             // epilogue patches (after barrier 2)

  const int tid  = threadIdx.x;
  const int lane = tid & 63;
  const int wv   = tid >> 6;
  const int c    = lane & 31;
  const int hl   = lane >> 5;
  const int wg   = ((int)blockIdx.x & 7) * 32 + ((int)blockIdx.x >> 3);
  const int r0   = wg * 256;
  const int b    = r0 >> 13;
  const int n    = (r0 & (S_ - 1)) >> 8;

  // x A-frags (needed only in O-GEMM; issued first to hide latency; L3-warm)
  bf16x8 afrag[8];
  {
    const float* xrow = x + (size_t)(r0 + wv * 32 + c) * 128 + hl * 8;
    #pragma unroll
    for (int kst = 0; kst < 8; ++kst) {
      const float4* p = (const float4*)(xrow + kst * 16);
      float4 f0 = p[0], f1 = p[1];
      bf16x8 a;
      a[0] = f2bf(f0.x); a[1] = f2bf(f0.y); a[2] = f2bf(f0.z); a[3] = f2bf(f0.w);
      a[4] = f2bf(f1.x); a[5] = f2bf(f1.y); a[6] = f2bf(f1.z); a[7] = f2bf(f1.w);
      afrag[kst] = a;
    }
  }

  // stage Wq TRANSPOSED: read Wq[f][d4..+3] coalesced, write wqT[d][f]
  #pragma unroll
  for (int it = 0; it < 8; ++it) {
    int l  = it * 512 + tid;
    int f  = l >> 5;
    int d4 = (l & 31) << 2;
    const float4 w = *(const float4*)(Wq + f * 128 + d4);
    wqT[(d4 + 0) * LDW + f] = f2bf(w.x);
    wqT[(d4 + 1) * LDW + f] = f2bf(w.y);
    wqT[(d4 + 2) * LDW + f] = f2bf(w.z);
    wqT[(d4 + 3) * LDW + f] = f2bf(w.w);
  }

  // ---- phase A ----
  float m[32];
  #pragma unroll
  for (int i = 0; i < 32; ++i) m[i] = 0.f;

  const float* Cb0 = Cpart + (size_t)b * 64 * 16384;
  #pragma unroll
  for (int e = 0; e < 6; ++e) {
    int hj = 2 * n - 2 + e;
    if (hj < 0 || hj >= 64) continue;         // wave-uniform branch
    const float4* Cp = (const float4*)(Cb0 + (size_t)hj * 16384);
    #pragma unroll
    for (int i4 = 0; i4 < 8; ++i4) {
      float4 f = Cp[i4 * 512 + tid];
      m[i4 * 4 + 0] += f.x; m[i4 * 4 + 1] += f.y;
      m[i4 * 4 + 2] += f.z; m[i4 * 4 + 3] += f.w;
    }
  }

  const int d0 = (tid & 31) << 2;
  if (n > 0) {   // subtract key a = (n-1)*256  (slot 0 of block n-1)
    const short* ke = kedge + ((size_t)(b * 32 + n - 1)) * 256;
    const short* ve = vedge + ((size_t)(b * 32 + n - 1)) * 256;
    float k0 = bf2f(ke[d0]),     k1 = bf2f(ke[d0 + 1]);
    float k2 = bf2f(ke[d0 + 2]), k3 = bf2f(ke[d0 + 3]);
    #pragma unroll
    for (int i4 = 0; i4 < 8; ++i4) {
      float vs = bf2f(ve[i4 * 16 + (tid >> 5)]);
      m[i4 * 4 + 0] -= vs * k0; m[i4 * 4 + 1] -= vs * k1;
      m[i4 * 4 + 2] -= vs * k2; m[i4 * 4 + 3] -= vs * k3;
    }
  }
  if (n < 31) {  // subtract key z = (n+1)*256+255  (slot 1 of block n+1)
    const short* ke = kedge + ((size_t)(b * 32 + n + 1)) * 256 + 128;
    const short* ve = vedge + ((size_t)(b * 32 + n + 1)) * 256 + 128;
    float k0 = bf2f(ke[d0]),     k1 = bf2f(ke[d0 + 1]);
    float k2 = bf2f(ke[d0 + 2]), k3 = bf2f(ke[d0 + 3]);
    #pragma unroll
    for (int i4 = 0; i4 < 8; ++i4) {
      float vs = bf2f(ve[i4 * 16 + (tid >> 5)]);
      m[i4 * 4 + 0] -= vs * k0; m[i4 * 4 + 1] -= vs * k1;
      m[i4 * 4 + 2] -= vs * k2; m[i4 * 4 + 3] -= vs * k3;
    }
  }

  const float scale = 0.08838834764831845f;   // 1/sqrt(128)
  // m_l write + bqM partials (over f = d0..d0+3 for 8 h's each)
  float4 bqv = *(const float4*)(bq + d0);
  float bp[8];
  #pragma unroll
  for (int i4 = 0; i4 < 8; ++i4) {
    int h = i4 * 16 + (tid >> 5);
    float m0 = m[i4 * 4 + 0] * scale, m1 = m[i4 * 4 + 1] * scale;
    float m2 = m[i4 * 4 + 2] * scale, m3 = m[i4 * 4 + 3] * scale;
    s16x4 o;
    o[0] = f2bf(m0); o[1] = f2bf(m1); o[2] = f2bf(m2); o[3] = f2bf(m3);
    *(s16x4*)(m_l + h * LDW + d0) = o;
    bp[i4] = m0 * bqv.x + m1 * bqv.y + m2 * bqv.z + m3 * bqv.w;
  }
  // reduce bqM over the 32 threads sharing each h (low 5 bits of tid)
  #pragma unroll
  for (int mask = 1; mask <= 16; mask <<= 1) {
    #pragma unroll
    for (int i4 = 0; i4 < 8; ++i4) bp[i4] += __shfl_xor(bp[i4], mask);
  }
  if ((tid & 31) == 0) {
    #pragma unroll
    for (int i4 = 0; i4 < 8; ++i4) bqM_l[i4 * 16 + (tid >> 5)] = bp[i4];
  }
  __syncthreads();   // barrier 1: wqT, m_l, bqM_l ready

  // ---- N-GEMM: N2[h][d] = sum_f m_l[h][f] * wqT[d][f] ----
  {
    const int ht2 = wv >> 1;        // 4 x 32 h-rows
    const int dc  = (wv & 1) * 64;  // 2 x 64 d-cols
    f32x16 nacc[2];
    #pragma unroll
    for (int t = 0; t < 2; ++t)
      #pragma unroll
      for (int i = 0; i < 16; ++i) nacc[t][i] = 0.f;

    #pragma unroll
    for (int kst = 0; kst < 8; ++kst) {
      bf16x8 a = *(const bf16x8*)(m_l + (ht2 * 32 + c) * LDW + kst * 16 + hl * 8);
      #pragma unroll
      for (int t = 0; t < 2; ++t) {
        bf16x8 bb = *(const bf16x8*)(wqT + (dc + t * 32 + c) * LDW + kst * 16 + hl * 8);
        nacc[t] = __builtin_amdgcn_mfma_f32_32x32x16_bf16(a, bb, nacc[t], 0, 0, 0);
      }
    }
    #pragma unroll
    for (int t = 0; t < 2; ++t) {
      #pragma unroll
      for (int reg = 0; reg < 16; ++reg) {
        int row = (reg & 3) + 8 * (reg >> 2) + 4 * hl;
        n_l[(ht2 * 32 + row) * LDW + dc + t * 32 + c] = f2bf(nacc[t][reg]);
      }
    }
  }
  __syncthreads();   // barrier 2: n_l ready; wqT/m_l dead (opat may alias)

  // ---- O-GEMM: O[s][h] = sum_d x[s][d] * n_l[h][d] + bqM[h] ----
  f32x16 oacc[4];
  #pragma unroll
  for (int nt = 0; nt < 4; ++nt)
    #pragma unroll
    for (int i = 0; i < 16; ++i) oacc[nt][i] = 0.f;

  #pragma unroll
  for (int kst = 0; kst < 8; ++kst) {
    #pragma unroll
    for (int nt = 0; nt < 4; ++nt) {
      bf16x8 bb = *(const bf16x8*)(n_l + (nt * 32 + c) * LDW + kst * 16 + hl * 8);
      oacc[nt] = __builtin_amdgcn_mfma_f32_32x32x16_bf16(afrag[kst], bb, oacc[nt], 0, 0, 0);
    }
  }

  // epilogue: + bias, per-wave LDS patch (32x36 f32) -> coalesced float4 stores
  float* patch = opat + wv * (32 * 36);
  float* outb  = out + ((size_t)r0 + wv * 32) * 128;
  #pragma unroll
  for (int nt = 0; nt < 4; ++nt) {
    float bias = bqM_l[nt * 32 + c];
    #pragma unroll
    for (int reg = 0; reg < 16; ++reg) {
      int row = (reg & 3) + 8 * (reg >> 2) + 4 * hl;
      patch[row * 36 + c] = oacc[nt][reg] + bias;
    }
    #pragma unroll
    for (int p = 0; p < 4; ++p) {
      int row = p * 8 + (lane >> 3);
      float4 vv = *(const float4*)(patch + row * 36 + (lane & 7) * 4);
      *(float4*)(outb + (size_t)row * 128 + nt * 32 + (lane & 7) * 4) = vv;
    }
  }
}

// ---------------------------------------------------------------------------
extern "C" void kernel_launch(void* const* d_in, const int* in_sizes, int n_in,
                              void* d_out, int out_size, void* d_ws, size_t ws_size,
                              hipStream_t stream) {
  const float* x  = (const float*)d_in[0];
  const float* Wq = (const float*)d_in[1];
  const float* bq = (const float*)d_in[2];
  const float* Wk = (const float*)d_in[3];
  const float* bk = (const float*)d_in[4];
  const float* Wv = (const float*)d_in[5];
  const float* bv = (const float*)d_in[6];
  float* out = (float*)d_out;

  float* Cpart = (float*)d_ws;                          // 8*64*128*128 f32 = 33.6MB
  short* kedge = (short*)(Cpart + (size_t)8 * 64 * 16384);
  short* vedge = kedge + (size_t)8 * 32 * 256;

  kv_kernel<<<512, 256, 0, stream>>>(x, Wk, bk, Wv, bv, Cpart, kedge, vedge);
  attn_kernel<<<256, 512, 0, stream>>>(x, Wq, bq, Cpart, kedge, vedge, out);
}

// Round 11
// 116.205 us; speedup vs baseline: 1.1332x; 1.1332x over previous
//
#include <hip/hip_runtime.h>
#include <stdint.h>

// BlockAttention: B=8, S=8192, D=H=128, BLOCK=256, WINDOW=256 (halo 255, W=766)
// No softmax => out_blk = Q_blk @ (scale*M_n) = x_blk @ N_n + 1 (x) bqM_n
//   where M_n^T = C_{n-1}^T + C_n^T + C_{n+1}^T - v_a(x)k_a - v_z(x)k_z,
//         N_n = Wq^T (scale*M_n)   (128x128, computed per block in-LDS),
//         bqM_n[h] = sum_f bq[f]*(scale*M_n)[f][h]  (rank-1 bias term).
// Q IS NEVER MATERIALIZED (no qb tensor, no Q GEMM in kv).
// kv_kernel:  256 blocks (b,n) x 512 thr, 4 phases: stage Wk+Wv | K+V GEMM |
//             both transposes | C-GEMM -> Cpart + edge rows.
// attn_kernel: 256 blocks x 512 thr, 2 barriers: phase A (3 C blocks +
//             rank-1 edges + bqM reduce) -> m_l; N-GEMM -> n_l; O = x*N + bias.
// Both grids share one bijective XCD swizzle so C_n write/read are L2-local.
// [r11 = verified r9 structure: best measured point, 118.0 us]

#define B_ 8
#define S_ 8192
#define LDW 136   // padded leading dim (shorts) for 128-wide tiles
#define LDT 264   // padded leading dim (shorts) for 256-wide K^T/V^T tiles

using bf16x8 = __attribute__((ext_vector_type(8))) short;   // 8 bf16 = 4 VGPRs
using s16x4  = __attribute__((ext_vector_type(4))) short;
using f32x16 = __attribute__((ext_vector_type(16))) float;

__device__ __forceinline__ short f2bf(float f) {
  union { float f; uint32_t u; } v; v.f = f;
  uint32_t r = v.u + 0x7fffu + ((v.u >> 16) & 1u);   // RNE
  return (short)(r >> 16);
}
__device__ __forceinline__ float bf2f(short s) {
  union { uint32_t u; float f; } v; v.u = ((uint32_t)(uint16_t)s) << 16;
  return v.f;
}

// ---------------------------------------------------------------------------
// kv_kernel: 256 blocks (b,n) x 512 threads (8 waves), 256 keys each.
// LDS: areaA (Wk -> K^T [128][LDT]) + areaB (Wv -> V^T), 2 x 67,584 B.
// 4 barriers total.
// ---------------------------------------------------------------------------
__global__ __launch_bounds__(512) void kv_kernel(
    const float* __restrict__ x,
    const float* __restrict__ Wk, const float* __restrict__ bk,
    const float* __restrict__ Wv, const float* __restrict__ bv,
    float* __restrict__ Cpart, short* __restrict__ kedge,
    short* __restrict__ vedge)
{
  __shared__ __align__(16) char smem[135168];
  short* areaA = (short*)smem;            // Wk stage -> K^T tile [d][s]
  short* areaB = (short*)(smem + 67584);  // Wv stage -> V^T tile [h][s]

  const int tid  = threadIdx.x;
  const int lane = tid & 63;
  const int wv   = tid >> 6;        // 0..7
  const int c    = lane & 31;
  const int hl   = lane >> 5;
  // bijective XCD swizzle (256 % 8 == 0): XCD k owns wg k*32..+32 (= batch k)
  const int wg   = ((int)blockIdx.x & 7) * 32 + ((int)blockIdx.x >> 3);
  const int r0   = wg * 256;
  const int b    = r0 >> 13;
  const int n    = (r0 & (S_ - 1)) >> 8;

  // A fragments from x: A[m=c][k=16*kst+8*hl+j], rows r0 + wv*32 + c
  bf16x8 afrag[8];
  {
    const float* xrow = x + (size_t)(r0 + wv * 32 + c) * 128 + hl * 8;
    #pragma unroll
    for (int kst = 0; kst < 8; ++kst) {
      const float4* p = (const float4*)(xrow + kst * 16);
      float4 f0 = p[0], f1 = p[1];
      bf16x8 a;
      a[0] = f2bf(f0.x); a[1] = f2bf(f0.y); a[2] = f2bf(f0.z); a[3] = f2bf(f0.w);
      a[4] = f2bf(f1.x); a[5] = f2bf(f1.y); a[6] = f2bf(f1.z); a[7] = f2bf(f1.w);
      afrag[kst] = a;
    }
  }

  auto stageW = [&](const float* W, short* wl) {   // 128x128 f32 -> bf16
    #pragma unroll
    for (int it = 0; it < 8; ++it) {
      int l  = it * 512 + tid;
      int nn = l >> 5;
      int k4 = (l & 31) << 2;
      const float4 f = *(const float4*)(W + nn * 128 + k4);
      s16x4 o;
      o[0] = f2bf(f.x); o[1] = f2bf(f.y); o[2] = f2bf(f.z); o[3] = f2bf(f.w);
      *(s16x4*)(wl + nn * LDW + k4) = o;
    }
  };

  auto gemm = [&](const float* bias, f32x16* acc, const short* wl) {
    #pragma unroll
    for (int nt = 0; nt < 4; ++nt) {
      float bvv = bias[nt * 32 + c];
      #pragma unroll
      for (int i = 0; i < 16; ++i) acc[nt][i] = bvv;
    }
    #pragma unroll
    for (int kst = 0; kst < 8; ++kst) {
      #pragma unroll
      for (int nt = 0; nt < 4; ++nt) {
        bf16x8 bb = *(const bf16x8*)(wl + (nt * 32 + c) * LDW + kst * 16 + hl * 8);
        acc[nt] = __builtin_amdgcn_mfma_f32_32x32x16_bf16(afrag[kst], bb, acc[nt], 0, 0, 0);
      }
    }
  };

  // C-tile layout: col=lane&31, row=(reg&3)+8*(reg>>2)+4*hl
  auto writeTransposedLDS = [&](f32x16* acc, short* wl) {   // wl[d][s], LDT rows
    #pragma unroll
    for (int nt = 0; nt < 4; ++nt) {
      int d = nt * 32 + c;
      #pragma unroll
      for (int g = 0; g < 4; ++g) {
        #pragma unroll
        for (int p = 0; p < 2; ++p) {
          int reg = g * 4 + p * 2;
          int sl  = wv * 32 + g * 8 + hl * 4 + p * 2;   // 0..255
          uint32_t pk = (uint32_t)(uint16_t)f2bf(acc[nt][reg]) |
                        ((uint32_t)(uint16_t)f2bf(acc[nt][reg + 1]) << 16);
          *(uint32_t*)(wl + d * LDT + sl) = pk;
        }
      }
    }
  };

  // ---- P1: stage Wk -> A, Wv -> B ----
  stageW(Wk, areaA);
  stageW(Wv, areaB);
  __syncthreads();

  // ---- P2: K GEMM(A) + V GEMM(B), one phase ----
  f32x16 kacc[4], vacc[4];
  gemm(bk, kacc, areaA);
  gemm(bv, vacc, areaB);
  __syncthreads();                   // weight reads done

  // ---- P3: K^T -> A, V^T -> B ----
  writeTransposedLDS(kacc, areaA);
  writeTransposedLDS(vacc, areaB);
  __syncthreads();

  // ---- P4: C-GEMM + edges + Cpart ----
  {
    const int ht = wv >> 1;          // 4 x 32 h-rows
    const int dh = wv & 1;           // 2 x 64 d-cols
    f32x16 cacc[2];
    #pragma unroll
    for (int t = 0; t < 2; ++t)
      #pragma unroll
      for (int i = 0; i < 16; ++i) cacc[t][i] = 0.f;

    #pragma unroll
    for (int kst = 0; kst < 16; ++kst) {
      bf16x8 a  = *(const bf16x8*)(areaB + (ht * 32 + c) * LDT + kst * 16 + hl * 8);
      bf16x8 b0 = *(const bf16x8*)(areaA + (dh * 64 + c) * LDT + kst * 16 + hl * 8);
      bf16x8 b1 = *(const bf16x8*)(areaA + (dh * 64 + 32 + c) * LDT + kst * 16 + hl * 8);
      cacc[0] = __builtin_amdgcn_mfma_f32_32x32x16_bf16(a, b0, cacc[0], 0, 0, 0);
      cacc[1] = __builtin_amdgcn_mfma_f32_32x32x16_bf16(a, b1, cacc[1], 0, 0, 0);
    }

    // edge rows: slot0 = key n*256 (tile col 0), slot1 = key n*256+255 (col 255)
    {
      size_t eo = ((size_t)(b * 32 + n)) * 256;
      if (tid < 128)      kedge[eo + tid]               = areaA[tid * LDT + 0];
      else if (tid < 256) kedge[eo + 128 + (tid - 128)] = areaA[(tid - 128) * LDT + 255];
      else if (tid < 384) vedge[eo + (tid - 256)]       = areaB[(tid - 256) * LDT + 0];
      else                vedge[eo + 128 + (tid - 384)] = areaB[(tid - 384) * LDT + 255];
    }

    float* Cp = Cpart + ((size_t)(b * 32 + n)) * 16384;   // [h][d] row-major
    #pragma unroll
    for (int t = 0; t < 2; ++t) {
      #pragma unroll
      for (int reg = 0; reg < 16; ++reg) {
        int row = (reg & 3) + 8 * (reg >> 2) + 4 * hl;
        Cp[(ht * 32 + row) * 128 + dh * 64 + t * 32 + c] = cacc[t][reg];
      }
    }
  }
}

// ---------------------------------------------------------------------------
// attn_kernel: 256 blocks (b,n) x 512 threads (8 waves). Q-free.
// Phase A: m[h][f] = scale*(sum 3 C - v_a k_a - v_z k_z); bqM shuffle-reduce;
//          m_l bf16.  (thread owns h = i4*16+(tid>>5), f = (tid&31)*4..+3)
// N-GEMM:  N2[h][d] = sum_f m_l[h][f] * Wq[f][d]   (B-op = wqT[d][f] rows d)
// O-GEMM:  O[s][h]  = sum_d x[s][d] * n_l[h][d] + bqM[h]
// LDS: wqT 34,816 | m_l 34,816 | n_l 34,816 | bqM 512; opat aliases [0,36864).
// ---------------------------------------------------------------------------
__global__ __launch_bounds__(512) void attn_kernel(
    const float* __restrict__ x,
    const float* __restrict__ Wq, const float* __restrict__ bq,
    const float* __restrict__ Cpart,
    const short* __restrict__ kedge, const short* __restrict__ vedge,
    float* __restrict__ out)
{
  __shared__ __align__(16) char smem[104960];
  short* wqT   = (short*)smem;             // [d][f] transposed Wq, bf16
  short* m_l   = (short*)(smem + 34816);   // [h][f] scale*M^T, bf16
  short* n_l   = (short*)(smem + 69632);   // [h][d] N2, bf16
  float* bqM_l = (float*)(smem + 104448);  // [128]
  float* opat  = (float*)smem;             // epilogue patches (after barrier 2)

  const int tid  = threadIdx.x;
  const int lane = tid & 63;
  const int wv   = tid >> 6;
  const int c    = lane & 31;
  const int hl   = lane >> 5;
  const int wg   = ((int)blockIdx.x & 7) * 32 + ((int)blockIdx.x >> 3);
  const int r0   = wg * 256;
  const int b    = r0 >> 13;
  const int n    = (r0 & (S_ - 1)) >> 8;

  // x A-frags (needed only in O-GEMM; issued first to hide latency; L3-warm)
  bf16x8 afrag[8];
  {
    const float* xrow = x + (size_t)(r0 + wv * 32 + c) * 128 + hl * 8;
    #pragma unroll
    for (int kst = 0; kst < 8; ++kst) {
      const float4* p = (const float4*)(xrow + kst * 16);
      float4 f0 = p[0], f1 = p[1];
      bf16x8 a;
      a[0] = f2bf(f0.x); a[1] = f2bf(f0.y); a[2] = f2bf(f0.z); a[3] = f2bf(f0.w);
      a[4] = f2bf(f1.x); a[5] = f2bf(f1.y); a[6] = f2bf(f1.z); a[7] = f2bf(f1.w);
      afrag[kst] = a;
    }
  }

  // stage Wq TRANSPOSED: read Wq[f][d4..+3] coalesced, write wqT[d][f]
  #pragma unroll
  for (int it = 0; it < 8; ++it) {
    int l  = it * 512 + tid;
    int f  = l >> 5;
    int d4 = (l & 31) << 2;
    const float4 w = *(const float4*)(Wq + f * 128 + d4);
    wqT[(d4 + 0) * LDW + f] = f2bf(w.x);
    wqT[(d4 + 1) * LDW + f] = f2bf(w.y);
    wqT[(d4 + 2) * LDW + f] = f2bf(w.z);
    wqT[(d4 + 3) * LDW + f] = f2bf(w.w);
  }

  // ---- phase A ----
  float m[32];
  #pragma unroll
  for (int i = 0; i < 32; ++i) m[i] = 0.f;

  const float* Cb0 = Cpart + (size_t)b * 32 * 16384;
  #pragma unroll
  for (int e = 0; e < 3; ++e) {
    int nn = n - 1 + e;
    if (nn < 0 || nn > 31) continue;          // wave-uniform branch
    const float4* Cp = (const float4*)(Cb0 + (size_t)nn * 16384);
    #pragma unroll
    for (int i4 = 0; i4 < 8; ++i4) {
      float4 f = Cp[i4 * 512 + tid];
      m[i4 * 4 + 0] += f.x; m[i4 * 4 + 1] += f.y;
      m[i4 * 4 + 2] += f.z; m[i4 * 4 + 3] += f.w;
    }
  }

  const int d0 = (tid & 31) << 2;
  if (n > 0) {   // subtract key a = (n-1)*256  (slot 0 of block n-1)
    const short* ke = kedge + ((size_t)(b * 32 + n - 1)) * 256;
    const short* ve = vedge + ((size_t)(b * 32 + n - 1)) * 256;
    float k0 = bf2f(ke[d0]),     k1 = bf2f(ke[d0 + 1]);
    float k2 = bf2f(ke[d0 + 2]), k3 = bf2f(ke[d0 + 3]);
    #pragma unroll
    for (int i4 = 0; i4 < 8; ++i4) {
      float vs = bf2f(ve[i4 * 16 + (tid >> 5)]);
      m[i4 * 4 + 0] -= vs * k0; m[i4 * 4 + 1] -= vs * k1;
      m[i4 * 4 + 2] -= vs * k2; m[i4 * 4 + 3] -= vs * k3;
    }
  }
  if (n < 31) {  // subtract key z = (n+1)*256+255  (slot 1 of block n+1)
    const short* ke = kedge + ((size_t)(b * 32 + n + 1)) * 256 + 128;
    const short* ve = vedge + ((size_t)(b * 32 + n + 1)) * 256 + 128;
    float k0 = bf2f(ke[d0]),     k1 = bf2f(ke[d0 + 1]);
    float k2 = bf2f(ke[d0 + 2]), k3 = bf2f(ke[d0 + 3]);
    #pragma unroll
    for (int i4 = 0; i4 < 8; ++i4) {
      float vs = bf2f(ve[i4 * 16 + (tid >> 5)]);
      m[i4 * 4 + 0] -= vs * k0; m[i4 * 4 + 1] -= vs * k1;
      m[i4 * 4 + 2] -= vs * k2; m[i4 * 4 + 3] -= vs * k3;
    }
  }

  const float scale = 0.08838834764831845f;   // 1/sqrt(128)
  // m_l write + bqM partials (over f = d0..d0+3 for 8 h's each)
  float4 bqv = *(const float4*)(bq + d0);
  float bp[8];
  #pragma unroll
  for (int i4 = 0; i4 < 8; ++i4) {
    int h = i4 * 16 + (tid >> 5);
    float m0 = m[i4 * 4 + 0] * scale, m1 = m[i4 * 4 + 1] * scale;
    float m2 = m[i4 * 4 + 2] * scale, m3 = m[i4 * 4 + 3] * scale;
    s16x4 o;
    o[0] = f2bf(m0); o[1] = f2bf(m1); o[2] = f2bf(m2); o[3] = f2bf(m3);
    *(s16x4*)(m_l + h * LDW + d0) = o;
    bp[i4] = m0 * bqv.x + m1 * bqv.y + m2 * bqv.z + m3 * bqv.w;
  }
  // reduce bqM over the 32 threads sharing each h (low 5 bits of tid)
  #pragma unroll
  for (int mask = 1; mask <= 16; mask <<= 1) {
    #pragma unroll
    for (int i4 = 0; i4 < 8; ++i4) bp[i4] += __shfl_xor(bp[i4], mask);
  }
  if ((tid & 31) == 0) {
    #pragma unroll
    for (int i4 = 0; i4 < 8; ++i4) bqM_l[i4 * 16 + (tid >> 5)] = bp[i4];
  }
  __syncthreads();   // barrier 1: wqT, m_l, bqM_l ready

  // ---- N-GEMM: N2[h][d] = sum_f m_l[h][f] * wqT[d][f] ----
  {
    const int ht2 = wv >> 1;        // 4 x 32 h-rows
    const int dc  = (wv & 1) * 64;  // 2 x 64 d-cols
    f32x16 nacc[2];
    #pragma unroll
    for (int t = 0; t < 2; ++t)
      #pragma unroll
      for (int i = 0; i < 16; ++i) nacc[t][i] = 0.f;

    #pragma unroll
    for (int kst = 0; kst < 8; ++kst) {
      bf16x8 a = *(const bf16x8*)(m_l + (ht2 * 32 + c) * LDW + kst * 16 + hl * 8);
      #pragma unroll
      for (int t = 0; t < 2; ++t) {
        bf16x8 bb = *(const bf16x8*)(wqT + (dc + t * 32 + c) * LDW + kst * 16 + hl * 8);
        nacc[t] = __builtin_amdgcn_mfma_f32_32x32x16_bf16(a, bb, nacc[t], 0, 0, 0);
      }
    }
    // D[m=h][n=d]: col=lane&31=d-within, row=(reg&3)+8*(reg>>2)+4*hl
    #pragma unroll
    for (int t = 0; t < 2; ++t) {
      #pragma unroll
      for (int reg = 0; reg < 16; ++reg) {
        int row = (reg & 3) + 8 * (reg >> 2) + 4 * hl;
        n_l[(ht2 * 32 + row) * LDW + dc + t * 32 + c] = f2bf(nacc[t][reg]);
      }
    }
  }
  __syncthreads();   // barrier 2: n_l ready; wqT/m_l dead (opat may alias)

  // ---- O-GEMM: O[s][h] = sum_d x[s][d] * n_l[h][d] + bqM[h] ----
  f32x16 oacc[4];
  #pragma unroll
  for (int nt = 0; nt < 4; ++nt)
    #pragma unroll
    for (int i = 0; i < 16; ++i) oacc[nt][i] = 0.f;

  #pragma unroll
  for (int kst = 0; kst < 8; ++kst) {
    #pragma unroll
    for (int nt = 0; nt < 4; ++nt) {
      bf16x8 bb = *(const bf16x8*)(n_l + (nt * 32 + c) * LDW + kst * 16 + hl * 8);
      oacc[nt] = __builtin_amdgcn_mfma_f32_32x32x16_bf16(afrag[kst], bb, oacc[nt], 0, 0, 0);
    }
  }

  // epilogue: + bias, per-wave LDS patch (32x36 f32) -> coalesced float4 stores
  float* patch = opat + wv * (32 * 36);
  float* outb  = out + ((size_t)r0 + wv * 32) * 128;
  #pragma unroll
  for (int nt = 0; nt < 4; ++nt) {
    float bias = bqM_l[nt * 32 + c];
    #pragma unroll
    for (int reg = 0; reg < 16; ++reg) {
      int row = (reg & 3) + 8 * (reg >> 2) + 4 * hl;
      patch[row * 36 + c] = oacc[nt][reg] + bias;
    }
    #pragma unroll
    for (int p = 0; p < 4; ++p) {
      int row = p * 8 + (lane >> 3);
      float4 vv = *(const float4*)(patch + row * 36 + (lane & 7) * 4);
      *(float4*)(outb + (size_t)row * 128 + nt * 32 + (lane & 7) * 4) = vv;
    }
  }
}

// ---------------------------------------------------------------------------
extern "C" void kernel_launch(void* const* d_in, const int* in_sizes, int n_in,
                              void* d_out, int out_size, void* d_ws, size_t ws_size,
                              hipStream_t stream) {
  const float* x  = (const float*)d_in[0];
  const float* Wq = (const float*)d_in[1];
  const float* bq = (const float*)d_in[2];
  const float* Wk = (const float*)d_in[3];
  const float* bk = (const float*)d_in[4];
  const float* Wv = (const float*)d_in[5];
  const float* bv = (const float*)d_in[6];
  float* out = (float*)d_out;

  float* Cpart = (float*)d_ws;                          // 8*32*128*128 f32 = 16.8MB
  short* kedge = (short*)(Cpart + (size_t)8 * 32 * 16384);
  short* vedge = kedge + (size_t)8 * 32 * 256;

  kv_kernel<<<256, 512, 0, stream>>>(x, Wk, bk, Wv, bv, Cpart, kedge, vedge);
  attn_kernel<<<256, 512, 0, stream>>>(x, Wq, bq, Cpart, kedge, vedge, out);
}